// Round 1
// baseline (796.574 us; speedup 1.0000x reference)
//
#include <hip/hip_runtime.h>
#include <hip/hip_fp16.h>

#define BATCH   65536
#define IN_DIM  784
#define KPAD    800      // padded K per half (hi or lo)
#define K2      1600     // total GEMM K = [hi | lo]
#define H_DIM   1024
#define C_DIM   10
#define BN_EPS  1e-5f

typedef _Float16 half8 __attribute__((ext_vector_type(8)));
typedef _Float16 half4 __attribute__((ext_vector_type(4)));
typedef float    f32x4 __attribute__((ext_vector_type(4)));

#if defined(__has_builtin)
#if __has_builtin(__builtin_amdgcn_global_load_lds)
#define HAVE_ASYNC 1
#endif
#endif
#ifndef HAVE_ASYNC
#define HAVE_ASYNC 0
#endif

// Stage 16B/lane from global into LDS. Async path: wave-uniform LDS base,
// HW scatters lane i -> base + i*16 (layout must be contiguous in lane order).
__device__ __forceinline__ void stage16(const _Float16* g, _Float16* ldsBase, int lane) {
#if HAVE_ASYNC
  __builtin_amdgcn_global_load_lds((const __attribute__((address_space(1))) void*)g,
                                   (__attribute__((address_space(3))) void*)ldsBase,
                                   16, 0, 0);
#else
  *(half8*)(ldsBase + lane * 8) = *(const half8*)g;
#endif
}

// ---------------------------------------------------------------------------
// K1: split x (fp32) into fp16 hi/lo halves, K-concatenated: X2[b] = [hi(784) 0pad | lo(784) 0pad]
// ---------------------------------------------------------------------------
__global__ __launch_bounds__(256) void split_x(const float* __restrict__ x,
                                               _Float16* __restrict__ X2) {
  const long tid = (long)blockIdx.x * 256 + threadIdx.x;   // BATCH*200 threads
  const long row = tid / 200;
  const int  q   = (int)(tid - row * 200);
  const int  k   = q * 4;
  half4 hi = {}, lo = {};
  if (k < IN_DIM) {                       // 784 = 4*196, exact
    const f32x4 v = *(const f32x4*)&x[row * IN_DIM + k];
#pragma unroll
    for (int i = 0; i < 4; ++i) {
      const _Float16 h = (_Float16)v[i];
      hi[i] = h;
      lo[i] = (_Float16)(v[i] - (float)h);
    }
  }
  _Float16* dst = X2 + row * K2 + k;
  *(half4*)dst = hi;
  *(half4*)(dst + KPAD) = lo;
}

// ---------------------------------------------------------------------------
// K2: weight prep. Blocks 0..1023: alpha1[j]=mean|w1[j]|, S2[j]=[sign|0pad|sign|0pad] fp16.
//     Blocks 1024..1033: bw2[c][j] = mean|w2[c]| * sign(w2[c][j]) fp32.
// ---------------------------------------------------------------------------
__global__ __launch_bounds__(256) void prep_w(const float* __restrict__ w1,
                                              const float* __restrict__ w2,
                                              float* __restrict__ alpha1,
                                              _Float16* __restrict__ S2,
                                              float* __restrict__ bw2) {
  __shared__ float red[4];
  const int tid = threadIdx.x, lane = tid & 63, wave = tid >> 6;
  const int j = blockIdx.x;
  if (j < H_DIM) {
    const float* wr = w1 + (long)j * IN_DIM;
    float s = 0.f;
    for (int k = tid; k < IN_DIM; k += 256) s += fabsf(wr[k]);
#pragma unroll
    for (int off = 32; off > 0; off >>= 1) s += __shfl_xor(s, off, 64);
    if (lane == 0) red[wave] = s;
    __syncthreads();
    if (tid == 0) alpha1[j] = (red[0] + red[1] + red[2] + red[3]) * (1.f / IN_DIM);
    _Float16* dr = S2 + (long)j * K2;
    for (int k = tid; k < KPAD; k += 256) {
      const float v = (k < IN_DIM) ? wr[k] : 0.f;
      const _Float16 sg = (_Float16)((v > 0.f) ? 1.f : ((v < 0.f) ? -1.f : 0.f));
      dr[k] = sg;
      dr[KPAD + k] = sg;
    }
  } else {
    const int c = j - H_DIM;
    const float* wr = w2 + (long)c * H_DIM;
    float s = 0.f;
    for (int k = tid; k < H_DIM; k += 256) s += fabsf(wr[k]);
#pragma unroll
    for (int off = 32; off > 0; off >>= 1) s += __shfl_xor(s, off, 64);
    if (lane == 0) red[wave] = s;
    __syncthreads();
    const float alpha = (red[0] + red[1] + red[2] + red[3]) * (1.f / H_DIM);
    for (int k = tid; k < H_DIM; k += 256) {
      const float v = wr[k];
      const float sg = (v > 0.f) ? 1.f : ((v < 0.f) ? -1.f : 0.f);
      bw2[(long)c * H_DIM + k] = alpha * sg;
    }
  }
}

// ---------------------------------------------------------------------------
// K3: GEMM1  H[b][j] = alpha1[j] * sum_k X2[b][k]*S2[j][k]   (M=65536,N=1024,K=1600)
// m97 structure: 128x128 tile, BK=32, 4 waves (2x2 of 64x64), mfma 16x16x32 f16,
// global_load_lds(16B) staging, ds_read_b128 fragments.
// ---------------------------------------------------------------------------
__global__ __launch_bounds__(256) void gemm1(const _Float16* __restrict__ X2,
                                             const _Float16* __restrict__ S2,
                                             const float* __restrict__ alpha1,
                                             float* __restrict__ H) {
  __shared__ _Float16 As[128 * 32];
  __shared__ _Float16 Bs[128 * 32];
  const int tid  = threadIdx.x;
  const int lane = tid & 63;
  const int wave = tid >> 6;
  const int m0 = blockIdx.y * 128;
  const int n0 = blockIdx.x * 128;
  const int wm = (wave >> 1) * 64;
  const int wn = (wave & 1) * 64;

  // staging: wave stages 32 rows of A and 32 rows of B (two 16-row instrs each)
  const long aRow = (long)(m0 + wave * 32 + (lane >> 2));
  const long bRow = (long)(n0 + wave * 32 + (lane >> 2));
  const _Float16* aG = X2 + aRow * K2 + (lane & 3) * 8;
  const _Float16* bG = S2 + bRow * K2 + (lane & 3) * 8;
  _Float16* aL  = &As[(wave * 32) * 32];
  _Float16* aL2 = &As[(wave * 32 + 16) * 32];
  _Float16* bL  = &Bs[(wave * 32) * 32];
  _Float16* bL2 = &Bs[(wave * 32 + 16) * 32];

  f32x4 acc[4][4] = {};
  const int fr = lane & 15;         // m (A) / n (B) within 16
  const int kg = (lane >> 4) * 8;   // K sub-chunk

  for (int ks = 0; ks < K2 / 32; ++ks) {
    const int k0 = ks * 32;
    __syncthreads();
    stage16(aG + k0, aL, lane);
    stage16(aG + 16 * K2 + k0, aL2, lane);
    stage16(bG + k0, bL, lane);
    stage16(bG + 16 * K2 + k0, bL2, lane);
    __syncthreads();
    half8 af[4], bf[4];
#pragma unroll
    for (int i = 0; i < 4; ++i)
      af[i] = *(const half8*)&As[(wm + i * 16 + fr) * 32 + kg];
#pragma unroll
    for (int i = 0; i < 4; ++i)
      bf[i] = *(const half8*)&Bs[(wn + i * 16 + fr) * 32 + kg];
#pragma unroll
    for (int mi = 0; mi < 4; ++mi)
#pragma unroll
      for (int ni = 0; ni < 4; ++ni)
        acc[mi][ni] = __builtin_amdgcn_mfma_f32_16x16x32_f16(af[mi], bf[ni], acc[mi][ni], 0, 0, 0);
  }

  // epilogue: D layout col=lane&15, row=(lane>>4)*4+r  [measured m89/m91]
  const int rq = (lane >> 4) * 4;
#pragma unroll
  for (int ni = 0; ni < 4; ++ni) {
    const int col = n0 + wn + ni * 16 + fr;
    const float a1 = alpha1[col];
#pragma unroll
    for (int mi = 0; mi < 4; ++mi) {
#pragma unroll
      for (int r = 0; r < 4; ++r) {
        const int row = m0 + wm + mi * 16 + rq + r;
        H[(long)row * H_DIM + col] = acc[mi][ni][r] * a1;
      }
    }
  }
}

// ---------------------------------------------------------------------------
// K4: column sums / sumsq of H (for batch mean/var). 256 blocks x 256 rows.
// Thread t owns cols 4t..4t+3; one atomicAdd per col per block (256 adds/addr).
// ---------------------------------------------------------------------------
__global__ __launch_bounds__(256) void stats_k(const float* __restrict__ H,
                                               float* __restrict__ colsum,
                                               float* __restrict__ colsumsq) {
  const int t = threadIdx.x;
  const long row0 = (long)blockIdx.x * 256;
  const int col = t * 4;
  f32x4 s = {}, q = {};
  for (int r = 0; r < 256; ++r) {
    const f32x4 v = *(const f32x4*)&H[(row0 + r) * H_DIM + col];
#pragma unroll
    for (int i = 0; i < 4; ++i) { s[i] += v[i]; q[i] += v[i] * v[i]; }
  }
#pragma unroll
  for (int i = 0; i < 4; ++i) {
    atomicAdd(&colsum[col + i], s[i]);
    atomicAdd(&colsumsq[col + i], q[i]);
  }
}

// ---------------------------------------------------------------------------
// K5: normalize -> sign -> out = a @ bw2^T. One wave per batch row.
// ---------------------------------------------------------------------------
__global__ __launch_bounds__(256) void final_k(const float* __restrict__ H,
                                               const float* __restrict__ colsum,
                                               const float* __restrict__ colsumsq,
                                               const float* __restrict__ gamma,
                                               const float* __restrict__ beta,
                                               const float* __restrict__ bw2,
                                               float* __restrict__ out) {
  __shared__ float cs[H_DIM], ts[H_DIM];
  __shared__ float w2s[C_DIM * H_DIM];   // [oc][j] layout -> b128, conflict-free
  const int tid = threadIdx.x, lane = tid & 63, wave = tid >> 6;
  for (int j = tid; j < H_DIM; j += 256) {
    const float mu  = colsum[j] * (1.f / BATCH);
    const float var = colsumsq[j] * (1.f / BATCH) - mu * mu;  // biased var
    const float c   = gamma[j] * rsqrtf(var + BN_EPS);
    cs[j] = c;
    ts[j] = beta[j] - c * mu;             // sign(gamma*(h-mu)*invstd+beta) = sign(c*h+t)
  }
  for (int i = tid; i < C_DIM * H_DIM; i += 256) w2s[i] = bw2[i];
  __syncthreads();

  for (long row = (long)blockIdx.x * 4 + wave; row < BATCH; row += (long)gridDim.x * 4) {
    float p[C_DIM] = {};
#pragma unroll
    for (int c4 = 0; c4 < 4; ++c4) {
      const int col = c4 * 256 + lane * 4;
      const f32x4 v  = *(const f32x4*)&H[row * H_DIM + col];
      const f32x4 cv = *(const f32x4*)&cs[col];
      const f32x4 tv = *(const f32x4*)&ts[col];
      f32x4 a;
#pragma unroll
      for (int i = 0; i < 4; ++i) {
        const float hv = v[i] * cv[i] + tv[i];
        a[i] = (hv > 0.f) ? 1.f : ((hv < 0.f) ? -1.f : 0.f);   // jnp.sign semantics
      }
#pragma unroll
      for (int oc = 0; oc < C_DIM; ++oc) {
        const f32x4 w = *(const f32x4*)&w2s[oc * H_DIM + col];
        p[oc] += a[0] * w[0] + a[1] * w[1] + a[2] * w[2] + a[3] * w[3];
      }
    }
#pragma unroll
    for (int oc = 0; oc < C_DIM; ++oc)
#pragma unroll
      for (int off = 32; off > 0; off >>= 1)
        p[oc] += __shfl_xor(p[oc], off, 64);
    if (lane == 0) {
#pragma unroll
      for (int oc = 0; oc < C_DIM; ++oc) out[row * C_DIM + oc] = p[oc];
    }
  }
}

// ---------------------------------------------------------------------------
extern "C" void kernel_launch(void* const* d_in, const int* in_sizes, int n_in,
                              void* d_out, int out_size, void* d_ws, size_t ws_size,
                              hipStream_t stream) {
  const float* x     = (const float*)d_in[0];
  const float* w1    = (const float*)d_in[1];
  const float* w2    = (const float*)d_in[2];
  const float* gamma = (const float*)d_in[3];
  const float* beta  = (const float*)d_in[4];
  float* out = (float*)d_out;

  // workspace layout (bytes), all 256B-aligned offsets; total ~481.5 MB
  char* ws = (char*)d_ws;
  _Float16* X2     = (_Float16*)(ws + 0);            // 65536*1600*2 = 209,715,200
  float*    H      = (float*)  (ws + 209715200LL);   // 65536*1024*4 = 268,435,456
  _Float16* S2     = (_Float16*)(ws + 478150656LL);  // 1024*1600*2  =   3,276,800
  float*    BW2    = (float*)  (ws + 481427456LL);   // 10*1024*4    =      40,960
  float*    ALPHA1 = (float*)  (ws + 481468416LL);   // 1024*4       =       4,096
  float*    COLS   = (float*)  (ws + 481472512LL);   // 1024*4
  float*    COLQ   = (float*)  (ws + 481476608LL);   // 1024*4 (contiguous w/ COLS)

  hipMemsetAsync(COLS, 0, 2 * H_DIM * sizeof(float), stream);  // ws is poisoned each call
  split_x<<<(BATCH * 200) / 256, 256, 0, stream>>>(x, X2);
  prep_w<<<H_DIM + C_DIM, 256, 0, stream>>>(w1, w2, ALPHA1, S2, BW2);
  gemm1<<<dim3(H_DIM / 128, BATCH / 128), 256, 0, stream>>>(X2, S2, ALPHA1, H);
  stats_k<<<BATCH / 256, 256, 0, stream>>>(H, COLS, COLQ);
  final_k<<<2048, 256, 0, stream>>>(H, COLS, COLQ, gamma, beta, BW2, out);
}

// Round 2
// 752.926 us; speedup vs baseline: 1.0580x; 1.0580x over previous
//
#include <hip/hip_runtime.h>
#include <hip/hip_fp16.h>

#define BATCH   65536
#define IN_DIM  784
#define KPAD    800      // padded K per half (hi or lo)
#define K2      1600     // total GEMM K = [hi | lo]
#define H_DIM   1024
#define C_DIM   10
#define BN_EPS  1e-5f

typedef _Float16 half8 __attribute__((ext_vector_type(8)));
typedef _Float16 half4 __attribute__((ext_vector_type(4)));
typedef float    f32x4 __attribute__((ext_vector_type(4)));

#if defined(__has_builtin)
#if __has_builtin(__builtin_amdgcn_global_load_lds)
#define HAVE_ASYNC 1
#endif
#endif
#ifndef HAVE_ASYNC
#define HAVE_ASYNC 0
#endif

// Stage 16B/lane from global into LDS. Async path: wave-uniform LDS base,
// HW scatters lane i -> base + i*16 (layout contiguous in lane order).
__device__ __forceinline__ void stage16(const _Float16* g, _Float16* ldsBase, int lane) {
#if HAVE_ASYNC
  __builtin_amdgcn_global_load_lds((const __attribute__((address_space(1))) void*)g,
                                   (__attribute__((address_space(3))) void*)ldsBase,
                                   16, 0, 0);
#else
  *(half8*)(ldsBase + lane * 8) = *(const half8*)g;
#endif
}

// ---------------------------------------------------------------------------
// K1: split x (fp32) into fp16 hi/lo halves, K-concatenated:
//     X2[b] = [hi(784) 0pad | lo(784) 0pad]
// ---------------------------------------------------------------------------
__global__ __launch_bounds__(256) void split_x(const float* __restrict__ x,
                                               _Float16* __restrict__ X2) {
  const long tid = (long)blockIdx.x * 256 + threadIdx.x;   // BATCH*200 threads
  const long row = tid / 200;
  const int  q   = (int)(tid - row * 200);
  const int  k   = q * 4;
  half4 hi = {}, lo = {};
  if (k < IN_DIM) {                       // 784 = 4*196, exact
    const f32x4 v = *(const f32x4*)&x[row * IN_DIM + k];
#pragma unroll
    for (int i = 0; i < 4; ++i) {
      const _Float16 h = (_Float16)v[i];
      hi[i] = h;
      lo[i] = (_Float16)(v[i] - (float)h);
    }
  }
  _Float16* dst = X2 + row * K2 + k;
  *(half4*)dst = hi;
  *(half4*)(dst + KPAD) = lo;
}

// ---------------------------------------------------------------------------
// K2: weight prep. Blocks 0..1023: alpha1[j]=mean|w1[j]|, S2[j]=[sign|0pad|sign|0pad] fp16.
//     Blocks 1024..1033: bw2[c][j] = mean|w2[c]| * sign(w2[c][j]) fp32.
// ---------------------------------------------------------------------------
__global__ __launch_bounds__(256) void prep_w(const float* __restrict__ w1,
                                              const float* __restrict__ w2,
                                              float* __restrict__ alpha1,
                                              _Float16* __restrict__ S2,
                                              float* __restrict__ bw2) {
  __shared__ float red[4];
  const int tid = threadIdx.x, lane = tid & 63, wave = tid >> 6;
  const int j = blockIdx.x;
  if (j < H_DIM) {
    const float* wr = w1 + (long)j * IN_DIM;
    float s = 0.f;
    for (int k = tid; k < IN_DIM; k += 256) s += fabsf(wr[k]);
#pragma unroll
    for (int off = 32; off > 0; off >>= 1) s += __shfl_xor(s, off, 64);
    if (lane == 0) red[wave] = s;
    __syncthreads();
    if (tid == 0) alpha1[j] = (red[0] + red[1] + red[2] + red[3]) * (1.f / IN_DIM);
    _Float16* dr = S2 + (long)j * K2;
    for (int k = tid; k < KPAD; k += 256) {
      const float v = (k < IN_DIM) ? wr[k] : 0.f;
      const _Float16 sg = (_Float16)((v > 0.f) ? 1.f : ((v < 0.f) ? -1.f : 0.f));
      dr[k] = sg;
      dr[KPAD + k] = sg;
    }
  } else {
    const int c = j - H_DIM;
    const float* wr = w2 + (long)c * H_DIM;
    float s = 0.f;
    for (int k = tid; k < H_DIM; k += 256) s += fabsf(wr[k]);
#pragma unroll
    for (int off = 32; off > 0; off >>= 1) s += __shfl_xor(s, off, 64);
    if (lane == 0) red[wave] = s;
    __syncthreads();
    const float alpha = (red[0] + red[1] + red[2] + red[3]) * (1.f / H_DIM);
    for (int k = tid; k < H_DIM; k += 256) {
      const float v = wr[k];
      const float sg = (v > 0.f) ? 1.f : ((v < 0.f) ? -1.f : 0.f);
      bw2[(long)c * H_DIM + k] = alpha * sg;
    }
  }
}

// ---------------------------------------------------------------------------
// K3: GEMM1  H[b][j] = alpha1[j] * sum_k X2[b][k]*S2[j][k]   (M=65536,N=1024,K=1600)
// m97 structure (128x128 tile, BK=32, mfma 16x16x32 f16, global_load_lds 16B)
// + XOR-swizzled LDS (kills the 4x b128 bank conflicts) + fused BN col-stats.
//
// Swizzle: LDS dest of global_load_lds is lane-ordered (slot = lane), so we
// permute the SOURCE: lane i fetches k-chunk (i&3)^((i>>3)&3) of row i>>2.
// => slot(r,kc) = r*4 + (kc ^ ((r>>1)&3)). Fragment read at fixed kc=lane>>4
// then has slot%8 = 4*(fr&1) + (kc^((fr>>1)&3)): each of the 8 bank-groups
// gets exactly 2 of the 16 quarter-wave lanes -> 2-way (free, m136).
// ---------------------------------------------------------------------------
__global__ __launch_bounds__(256) void gemm1(const _Float16* __restrict__ X2,
                                             const _Float16* __restrict__ S2,
                                             const float* __restrict__ alpha1,
                                             float* __restrict__ H,
                                             float* __restrict__ colsum,
                                             float* __restrict__ colsumsq) {
  __shared__ _Float16 As[128 * 32];
  __shared__ _Float16 Bs[128 * 32];
  const int tid  = threadIdx.x;
  const int lane = tid & 63;
  const int wave = tid >> 6;
  const int m0 = blockIdx.y * 128;
  const int n0 = blockIdx.x * 128;
  const int wm = (wave >> 1) * 64;
  const int wn = (wave & 1) * 64;

  // staging: swizzled source chunk per lane
  const int  kcg  = (lane & 3) ^ ((lane >> 3) & 3);
  const long aRow = (long)(m0 + wave * 32 + (lane >> 2));
  const long bRow = (long)(n0 + wave * 32 + (lane >> 2));
  const _Float16* aG = X2 + aRow * K2 + kcg * 8;
  const _Float16* bG = S2 + bRow * K2 + kcg * 8;
  _Float16* aL  = &As[(wave * 32) * 32];
  _Float16* aL2 = &As[(wave * 32 + 16) * 32];
  _Float16* bL  = &Bs[(wave * 32) * 32];
  _Float16* bL2 = &Bs[(wave * 32 + 16) * 32];

  f32x4 acc[4][4] = {};
  const int fr = lane & 15;         // m (A) / n (B) within 16
  const int kc = lane >> 4;         // K 16B-chunk index
  // swizzled fragment read offset within a 16-row window (halves)
  const int frag = (fr * 4 + (kc ^ ((fr >> 1) & 3))) * 8;
  const int abase = (wm >> 4) * 512 + frag;   // window = 16 rows * 32 halves = 512
  const int bbase = (wn >> 4) * 512 + frag;

  for (int ks = 0; ks < K2 / 32; ++ks) {
    const int k0 = ks * 32;
    __syncthreads();
    stage16(aG + k0, aL, lane);
    stage16(aG + 16 * K2 + k0, aL2, lane);
    stage16(bG + k0, bL, lane);
    stage16(bG + 16 * K2 + k0, bL2, lane);
    __syncthreads();
    half8 af[4], bf[4];
#pragma unroll
    for (int i = 0; i < 4; ++i) af[i] = *(const half8*)&As[abase + i * 512];
#pragma unroll
    for (int i = 0; i < 4; ++i) bf[i] = *(const half8*)&Bs[bbase + i * 512];
#pragma unroll
    for (int mi = 0; mi < 4; ++mi)
#pragma unroll
      for (int ni = 0; ni < 4; ++ni)
        acc[mi][ni] = __builtin_amdgcn_mfma_f32_16x16x32_f16(af[mi], bf[ni], acc[mi][ni], 0, 0, 0);
  }

  // epilogue: D layout col=lane&15, row=(lane>>4)*4+r  [measured m89/m91]
  // + fused column sum/sumsq (lanes fr, fr+16, fr+32, fr+48 share col and
  //   together cover all 16 rows of each mi-subtile -> shfl_xor 16,32)
  const int rq = (lane >> 4) * 4;
#pragma unroll
  for (int ni = 0; ni < 4; ++ni) {
    const int col = n0 + wn + ni * 16 + fr;
    const float a1 = alpha1[col];
    float s = 0.f, q = 0.f;
#pragma unroll
    for (int mi = 0; mi < 4; ++mi) {
#pragma unroll
      for (int r = 0; r < 4; ++r) {
        const int row = m0 + wm + mi * 16 + rq + r;
        const float v = acc[mi][ni][r] * a1;
        H[(long)row * H_DIM + col] = v;
        s += v;
        q += v * v;
      }
    }
    s += __shfl_xor(s, 16, 64);
    s += __shfl_xor(s, 32, 64);
    q += __shfl_xor(q, 16, 64);
    q += __shfl_xor(q, 32, 64);
    if ((lane >> 4) == 0) {
      atomicAdd(&colsum[col], s);
      atomicAdd(&colsumsq[col], q);
    }
  }
}

// ---------------------------------------------------------------------------
// K5: normalize -> sign -> out = a @ bw2^T. One wave per batch row.
// ---------------------------------------------------------------------------
__global__ __launch_bounds__(256) void final_k(const float* __restrict__ H,
                                               const float* __restrict__ colsum,
                                               const float* __restrict__ colsumsq,
                                               const float* __restrict__ gamma,
                                               const float* __restrict__ beta,
                                               const float* __restrict__ bw2,
                                               float* __restrict__ out) {
  __shared__ float cs[H_DIM], ts[H_DIM];
  __shared__ float w2s[C_DIM * H_DIM];   // [oc][j] layout -> b128, conflict-free
  const int tid = threadIdx.x, lane = tid & 63, wave = tid >> 6;
  for (int j = tid; j < H_DIM; j += 256) {
    const float mu  = colsum[j] * (1.f / BATCH);
    const float var = colsumsq[j] * (1.f / BATCH) - mu * mu;  // biased var
    const float c   = gamma[j] * rsqrtf(var + BN_EPS);
    cs[j] = c;
    ts[j] = beta[j] - c * mu;             // sign(gamma*(h-mu)*invstd+beta) = sign(c*h+t)
  }
  for (int i = tid; i < C_DIM * H_DIM; i += 256) w2s[i] = bw2[i];
  __syncthreads();

  for (long row = (long)blockIdx.x * 4 + wave; row < BATCH; row += (long)gridDim.x * 4) {
    float p[C_DIM] = {};
#pragma unroll
    for (int c4 = 0; c4 < 4; ++c4) {
      const int col = c4 * 256 + lane * 4;
      const f32x4 v  = *(const f32x4*)&H[row * H_DIM + col];
      const f32x4 cv = *(const f32x4*)&cs[col];
      const f32x4 tv = *(const f32x4*)&ts[col];
      f32x4 a;
#pragma unroll
      for (int i = 0; i < 4; ++i) {
        const float hv = v[i] * cv[i] + tv[i];
        a[i] = (hv > 0.f) ? 1.f : ((hv < 0.f) ? -1.f : 0.f);   // jnp.sign semantics
      }
#pragma unroll
      for (int oc = 0; oc < C_DIM; ++oc) {
        const f32x4 w = *(const f32x4*)&w2s[oc * H_DIM + col];
        p[oc] += a[0] * w[0] + a[1] * w[1] + a[2] * w[2] + a[3] * w[3];
      }
    }
#pragma unroll
    for (int oc = 0; oc < C_DIM; ++oc)
#pragma unroll
      for (int off = 32; off > 0; off >>= 1)
        p[oc] += __shfl_xor(p[oc], off, 64);
    if (lane == 0) {
#pragma unroll
      for (int oc = 0; oc < C_DIM; ++oc) out[row * C_DIM + oc] = p[oc];
    }
  }
}

// ---------------------------------------------------------------------------
extern "C" void kernel_launch(void* const* d_in, const int* in_sizes, int n_in,
                              void* d_out, int out_size, void* d_ws, size_t ws_size,
                              hipStream_t stream) {
  const float* x     = (const float*)d_in[0];
  const float* w1    = (const float*)d_in[1];
  const float* w2    = (const float*)d_in[2];
  const float* gamma = (const float*)d_in[3];
  const float* beta  = (const float*)d_in[4];
  float* out = (float*)d_out;

  // workspace layout (bytes), all 256B-aligned offsets; total ~481.5 MB
  char* ws = (char*)d_ws;
  _Float16* X2     = (_Float16*)(ws + 0);            // 65536*1600*2 = 209,715,200
  float*    H      = (float*)  (ws + 209715200LL);   // 65536*1024*4 = 268,435,456
  _Float16* S2     = (_Float16*)(ws + 478150656LL);  // 1024*1600*2  =   3,276,800
  float*    BW2    = (float*)  (ws + 481427456LL);   // 10*1024*4    =      40,960
  float*    ALPHA1 = (float*)  (ws + 481468416LL);   // 1024*4       =       4,096
  float*    COLS   = (float*)  (ws + 481472512LL);   // 1024*4
  float*    COLQ   = (float*)  (ws + 481476608LL);   // 1024*4 (contiguous w/ COLS)

  hipMemsetAsync(COLS, 0, 2 * H_DIM * sizeof(float), stream);  // ws is poisoned each call
  split_x<<<(BATCH * 200) / 256, 256, 0, stream>>>(x, X2);
  prep_w<<<H_DIM + C_DIM, 256, 0, stream>>>(w1, w2, ALPHA1, S2, BW2);
  gemm1<<<dim3(H_DIM / 128, BATCH / 128), 256, 0, stream>>>(X2, S2, ALPHA1, H, COLS, COLQ);
  final_k<<<2048, 256, 0, stream>>>(H, COLS, COLQ, gamma, beta, BW2, out);
}

// Round 3
// 704.405 us; speedup vs baseline: 1.1308x; 1.0689x over previous
//
#include <hip/hip_runtime.h>
#include <hip/hip_fp16.h>

#define BATCH   65536
#define IN_DIM  784
#define KPAD    800      // padded K per half (hi or lo)
#define K2      1600     // total GEMM K = [hi | lo]
#define H_DIM   1024
#define C_DIM   10
#define BN_EPS  1e-5f

typedef _Float16 half8 __attribute__((ext_vector_type(8)));
typedef _Float16 half4 __attribute__((ext_vector_type(4)));
typedef float    f32x4 __attribute__((ext_vector_type(4)));

#if defined(__has_builtin)
#if __has_builtin(__builtin_amdgcn_global_load_lds)
#define HAVE_ASYNC 1
#endif
#endif
#ifndef HAVE_ASYNC
#define HAVE_ASYNC 0
#endif

// Stage 16B/lane from global into LDS. Async path: wave-uniform LDS base,
// HW scatters lane i -> base + i*16 (layout contiguous in lane order).
__device__ __forceinline__ void stage16(const _Float16* g, _Float16* ldsBase, int lane) {
#if HAVE_ASYNC
  __builtin_amdgcn_global_load_lds((const __attribute__((address_space(1))) void*)g,
                                   (__attribute__((address_space(3))) void*)ldsBase,
                                   16, 0, 0);
#else
  *(half8*)(ldsBase + lane * 8) = *(const half8*)g;
#endif
}

// ---------------------------------------------------------------------------
// K1: split x (fp32) into fp16 hi/lo halves, K-concatenated:
//     X2[b] = [hi(784) 0pad | lo(784) 0pad]
// ---------------------------------------------------------------------------
__global__ __launch_bounds__(256) void split_x(const float* __restrict__ x,
                                               _Float16* __restrict__ X2) {
  const long tid = (long)blockIdx.x * 256 + threadIdx.x;   // BATCH*200 threads
  const long row = tid / 200;
  const int  q   = (int)(tid - row * 200);
  const int  k   = q * 4;
  half4 hi = {}, lo = {};
  if (k < IN_DIM) {                       // 784 = 4*196, exact
    const f32x4 v = *(const f32x4*)&x[row * IN_DIM + k];
#pragma unroll
    for (int i = 0; i < 4; ++i) {
      const _Float16 h = (_Float16)v[i];
      hi[i] = h;
      lo[i] = (_Float16)(v[i] - (float)h);
    }
  }
  _Float16* dst = X2 + row * K2 + k;
  *(half4*)dst = hi;
  *(half4*)(dst + KPAD) = lo;
}

// ---------------------------------------------------------------------------
// K2: weight prep. Blocks 0..1023: alpha1[j]=mean|w1[j]|, S2[j]=[sign|0pad|sign|0pad] fp16.
//     Blocks 1024..1033: bw2[c][j] = mean|w2[c]| * sign(w2[c][j]) fp32.
// ---------------------------------------------------------------------------
__global__ __launch_bounds__(256) void prep_w(const float* __restrict__ w1,
                                              const float* __restrict__ w2,
                                              float* __restrict__ alpha1,
                                              _Float16* __restrict__ S2,
                                              float* __restrict__ bw2) {
  __shared__ float red[4];
  const int tid = threadIdx.x, lane = tid & 63, wave = tid >> 6;
  const int j = blockIdx.x;
  if (j < H_DIM) {
    const float* wr = w1 + (long)j * IN_DIM;
    float s = 0.f;
    for (int k = tid; k < IN_DIM; k += 256) s += fabsf(wr[k]);
#pragma unroll
    for (int off = 32; off > 0; off >>= 1) s += __shfl_xor(s, off, 64);
    if (lane == 0) red[wave] = s;
    __syncthreads();
    if (tid == 0) alpha1[j] = (red[0] + red[1] + red[2] + red[3]) * (1.f / IN_DIM);
    _Float16* dr = S2 + (long)j * K2;
    for (int k = tid; k < KPAD; k += 256) {
      const float v = (k < IN_DIM) ? wr[k] : 0.f;
      const _Float16 sg = (_Float16)((v > 0.f) ? 1.f : ((v < 0.f) ? -1.f : 0.f));
      dr[k] = sg;
      dr[KPAD + k] = sg;
    }
  } else {
    const int c = j - H_DIM;
    const float* wr = w2 + (long)c * H_DIM;
    float s = 0.f;
    for (int k = tid; k < H_DIM; k += 256) s += fabsf(wr[k]);
#pragma unroll
    for (int off = 32; off > 0; off >>= 1) s += __shfl_xor(s, off, 64);
    if (lane == 0) red[wave] = s;
    __syncthreads();
    const float alpha = (red[0] + red[1] + red[2] + red[3]) * (1.f / H_DIM);
    for (int k = tid; k < H_DIM; k += 256) {
      const float v = wr[k];
      const float sg = (v > 0.f) ? 1.f : ((v < 0.f) ? -1.f : 0.f);
      bw2[(long)c * H_DIM + k] = alpha * sg;
    }
  }
}

// ---------------------------------------------------------------------------
// K3: GEMM1  H[b][j] = alpha1[j] * sum_k X2[b][k]*S2[j][k]   (M=65536,N=1024,K=1600)
// m97 structure + zero-conflict XOR swizzle (R2) + fused BN col-stats (R2)
// + XCD-aware block remap (R3):
//   HW dispatches block b to XCD b%8. We give each XCD 64 consecutive
//   m-tiles x all 8 n-tiles, n fastest -> an XCD's ~80 resident blocks
//   share ~10 A-slices (4 MB, fits its private L2) + all of S2 (3.3 MB).
//   A is then fetched from HBM once device-wide instead of ~4x (R2 counters:
//   FETCH 849 MB ~= 4x|X2|), turning staging waits from ~900cyc HBM-miss
//   into ~200cyc L2-hit.
// ---------------------------------------------------------------------------
__global__ __launch_bounds__(256) void gemm1(const _Float16* __restrict__ X2,
                                             const _Float16* __restrict__ S2,
                                             const float* __restrict__ alpha1,
                                             float* __restrict__ H,
                                             float* __restrict__ colsum,
                                             float* __restrict__ colsumsq) {
  __shared__ _Float16 As[128 * 32];
  __shared__ _Float16 Bs[128 * 32];
  const int tid  = threadIdx.x;
  const int lane = tid & 63;
  const int wave = tid >> 6;

  // XCD-aware remap: 4096 blocks -> (mt, nt); b%8 = XCD id on MI355X.
  const int b     = blockIdx.x;
  const int xcd   = b & 7;
  const int local = b >> 3;                 // 0..511, sequential within XCD
  const int m0 = (xcd * 64 + (local >> 3)) * 128;
  const int n0 = (local & 7) * 128;

  const int wm = (wave >> 1) * 64;
  const int wn = (wave & 1) * 64;

  // staging: swizzled source chunk per lane (zero-conflict, verified R2)
  const int  kcg  = (lane & 3) ^ ((lane >> 3) & 3);
  const long aRow = (long)(m0 + wave * 32 + (lane >> 2));
  const long bRow = (long)(n0 + wave * 32 + (lane >> 2));
  const _Float16* aG = X2 + aRow * K2 + kcg * 8;
  const _Float16* bG = S2 + bRow * K2 + kcg * 8;
  _Float16* aL  = &As[(wave * 32) * 32];
  _Float16* aL2 = &As[(wave * 32 + 16) * 32];
  _Float16* bL  = &Bs[(wave * 32) * 32];
  _Float16* bL2 = &Bs[(wave * 32 + 16) * 32];

  f32x4 acc[4][4] = {};
  const int fr = lane & 15;         // m (A) / n (B) within 16
  const int kc = lane >> 4;         // K 16B-chunk index
  const int frag = (fr * 4 + (kc ^ ((fr >> 1) & 3))) * 8;
  const int abase = (wm >> 4) * 512 + frag;   // window = 16 rows * 32 halves = 512
  const int bbase = (wn >> 4) * 512 + frag;

  for (int ks = 0; ks < K2 / 32; ++ks) {
    const int k0 = ks * 32;
    __syncthreads();
    stage16(aG + k0, aL, lane);
    stage16(aG + 16 * K2 + k0, aL2, lane);
    stage16(bG + k0, bL, lane);
    stage16(bG + 16 * K2 + k0, bL2, lane);
    __syncthreads();
    half8 af[4], bf[4];
#pragma unroll
    for (int i = 0; i < 4; ++i) af[i] = *(const half8*)&As[abase + i * 512];
#pragma unroll
    for (int i = 0; i < 4; ++i) bf[i] = *(const half8*)&Bs[bbase + i * 512];
#pragma unroll
    for (int mi = 0; mi < 4; ++mi)
#pragma unroll
      for (int ni = 0; ni < 4; ++ni)
        acc[mi][ni] = __builtin_amdgcn_mfma_f32_16x16x32_f16(af[mi], bf[ni], acc[mi][ni], 0, 0, 0);
  }

  // epilogue: D layout col=lane&15, row=(lane>>4)*4+r  [measured m89/m91]
  // + fused column sum/sumsq
  const int rq = (lane >> 4) * 4;
#pragma unroll
  for (int ni = 0; ni < 4; ++ni) {
    const int col = n0 + wn + ni * 16 + fr;
    const float a1 = alpha1[col];
    float s = 0.f, q = 0.f;
#pragma unroll
    for (int mi = 0; mi < 4; ++mi) {
#pragma unroll
      for (int r = 0; r < 4; ++r) {
        const int row = m0 + wm + mi * 16 + rq + r;
        const float v = acc[mi][ni][r] * a1;
        H[(long)row * H_DIM + col] = v;
        s += v;
        q += v * v;
      }
    }
    s += __shfl_xor(s, 16, 64);
    s += __shfl_xor(s, 32, 64);
    q += __shfl_xor(q, 16, 64);
    q += __shfl_xor(q, 32, 64);
    if ((lane >> 4) == 0) {
      atomicAdd(&colsum[col], s);
      atomicAdd(&colsumsq[col], q);
    }
  }
}

// ---------------------------------------------------------------------------
// K5: normalize -> sign -> out = a @ bw2^T. One wave per batch row.
// ---------------------------------------------------------------------------
__global__ __launch_bounds__(256) void final_k(const float* __restrict__ H,
                                               const float* __restrict__ colsum,
                                               const float* __restrict__ colsumsq,
                                               const float* __restrict__ gamma,
                                               const float* __restrict__ beta,
                                               const float* __restrict__ bw2,
                                               float* __restrict__ out) {
  __shared__ float cs[H_DIM], ts[H_DIM];
  __shared__ float w2s[C_DIM * H_DIM];   // [oc][j] layout -> b128, conflict-free
  const int tid = threadIdx.x, lane = tid & 63, wave = tid >> 6;
  for (int j = tid; j < H_DIM; j += 256) {
    const float mu  = colsum[j] * (1.f / BATCH);
    const float var = colsumsq[j] * (1.f / BATCH) - mu * mu;  // biased var
    const float c   = gamma[j] * rsqrtf(var + BN_EPS);
    cs[j] = c;
    ts[j] = beta[j] - c * mu;             // sign(gamma*(h-mu)*invstd+beta) = sign(c*h+t)
  }
  for (int i = tid; i < C_DIM * H_DIM; i += 256) w2s[i] = bw2[i];
  __syncthreads();

  for (long row = (long)blockIdx.x * 4 + wave; row < BATCH; row += (long)gridDim.x * 4) {
    float p[C_DIM] = {};
#pragma unroll
    for (int c4 = 0; c4 < 4; ++c4) {
      const int col = c4 * 256 + lane * 4;
      const f32x4 v  = *(const f32x4*)&H[row * H_DIM + col];
      const f32x4 cv = *(const f32x4*)&cs[col];
      const f32x4 tv = *(const f32x4*)&ts[col];
      f32x4 a;
#pragma unroll
      for (int i = 0; i < 4; ++i) {
        const float hv = v[i] * cv[i] + tv[i];
        a[i] = (hv > 0.f) ? 1.f : ((hv < 0.f) ? -1.f : 0.f);   // jnp.sign semantics
      }
#pragma unroll
      for (int oc = 0; oc < C_DIM; ++oc) {
        const f32x4 w = *(const f32x4*)&w2s[oc * H_DIM + col];
        p[oc] += a[0] * w[0] + a[1] * w[1] + a[2] * w[2] + a[3] * w[3];
      }
    }
#pragma unroll
    for (int oc = 0; oc < C_DIM; ++oc)
#pragma unroll
      for (int off = 32; off > 0; off >>= 1)
        p[oc] += __shfl_xor(p[oc], off, 64);
    if (lane == 0) {
#pragma unroll
      for (int oc = 0; oc < C_DIM; ++oc) out[row * C_DIM + oc] = p[oc];
    }
  }
}

// ---------------------------------------------------------------------------
extern "C" void kernel_launch(void* const* d_in, const int* in_sizes, int n_in,
                              void* d_out, int out_size, void* d_ws, size_t ws_size,
                              hipStream_t stream) {
  const float* x     = (const float*)d_in[0];
  const float* w1    = (const float*)d_in[1];
  const float* w2    = (const float*)d_in[2];
  const float* gamma = (const float*)d_in[3];
  const float* beta  = (const float*)d_in[4];
  float* out = (float*)d_out;

  // workspace layout (bytes), all 256B-aligned offsets; total ~481.5 MB
  char* ws = (char*)d_ws;
  _Float16* X2     = (_Float16*)(ws + 0);            // 65536*1600*2 = 209,715,200
  float*    H      = (float*)  (ws + 209715200LL);   // 65536*1024*4 = 268,435,456
  _Float16* S2     = (_Float16*)(ws + 478150656LL);  // 1024*1600*2  =   3,276,800
  float*    BW2    = (float*)  (ws + 481427456LL);   // 10*1024*4    =      40,960
  float*    ALPHA1 = (float*)  (ws + 481468416LL);   // 1024*4       =       4,096
  float*    COLS   = (float*)  (ws + 481472512LL);   // 1024*4
  float*    COLQ   = (float*)  (ws + 481476608LL);   // 1024*4 (contiguous w/ COLS)

  hipMemsetAsync(COLS, 0, 2 * H_DIM * sizeof(float), stream);  // ws is poisoned each call
  split_x<<<(BATCH * 200) / 256, 256, 0, stream>>>(x, X2);
  prep_w<<<H_DIM + C_DIM, 256, 0, stream>>>(w1, w2, ALPHA1, S2, BW2);
  gemm1<<<4096, 256, 0, stream>>>(X2, S2, ALPHA1, H, COLS, COLQ);
  final_k<<<2048, 256, 0, stream>>>(H, COLS, COLQ, gamma, beta, BW2, out);
}